// Round 19
// baseline (614.890 us; speedup 1.0000x reference)
//
#include <hip/hip_runtime.h>
#include <math.h>

#define EPS 1e-5f

// ---------------- float offsets in ws ----------------
#define OFF_A  0u          // conv1 out bf16 CHANNEL-LAST ushort[1024][121][224] (dead after kd5)
#define OFF_X0 0u          // tokens x [1024][81][64] fp32 (written after A dead)
#define OFF_Y  31850496u   // y [1024][81][64]
#define OFF_CP 31850496u   // BN1 partials [1024][448] (dead before fa writes Y)
#define OFF_WC 32374784u   // packed conv2 bf16 weights [64][9][224] ushort
#define OFF_B  47775744u   // conv2 out; after kd8: packed bf16 transformer weights
#define OFF_P  53084160u   // BN2 partials (dead after kd7 -> rotary table)
#define OFF_RT 53084160u   // rotary table [m 2][s 81][p 8][cu,su]
#define OFF_ST 53215232u   // scale1[8] shift1[8] scale2[64] shift2[64]

// packed bf16 transformer weight offsets (ushort units, base = (ushort*)(ws+OFF_B))
#define WB_QKV 0u          // [(l*2+p)*96+col]*64+k
#define WB_WG  24576u
#define WB_WO  32768u
#define WB_FW1 40960u
#define WB_FW2 57344u

typedef __attribute__((ext_vector_type(8))) short short8;
typedef __attribute__((ext_vector_type(4))) float f32x4;

__device__ inline unsigned short f2bf(float f) {
  unsigned int x = __float_as_uint(f);
  unsigned int r = x + 0x7fffu + ((x >> 16) & 1u);
  return (unsigned short)(r >> 16);
}
__device__ inline float bf2f(unsigned short h) {
  return __uint_as_float(((unsigned int)h) << 16);
}

// ---------------- kd1 v3: conv3d + bias -> A bf16 channel-last; fused BN1 partials ----------------
__global__ __launch_bounds__(256) void kd1_conv1(const float* X, const float* c3w,
                                                 const float* c3b, float* ws) {
  __shared__ float Xi[5070];
  __shared__ float w3[216];
  int tid = threadIdx.x, b = blockIdx.x;
  for (int u = tid; u < 5070; u += 256) Xi[u] = X[(size_t)b*5070 + u];
  if (tid < 216) w3[tid] = c3w[tid];
  __syncthreads();
  if (tid >= 224) return;
  int o1 = tid / 28, dd = tid - o1*28;
  float wr[27];
#pragma unroll
  for (int k = 0; k < 27; ++k) wr[k] = w3[o1*27 + k];
  float bias = c3b[o1];
  unsigned short* Ao = (unsigned short*)(ws + OFF_A) + (size_t)b*27104;
  float S = 0.f, Q = 0.f;
  for (int h = 0; h < 11; ++h) {
    const float* base = Xi + dd*169 + h*13;
    float c0[9], c1[9], c2[9];
#pragma unroll
    for (int j = 0; j < 9; ++j) {
      int kd = j / 3, kh = j - kd*3;
      const float* rp = base + kd*169 + kh*13;
      c0[j] = rp[0]; c1[j] = rp[1]; c2[j] = rp[2];
    }
#pragma unroll
    for (int w = 0; w < 11; ++w) {
      float a = bias;
#pragma unroll
      for (int j = 0; j < 9; ++j) {
        a = fmaf(c0[j], wr[j*3+0], a);
        a = fmaf(c1[j], wr[j*3+1], a);
        a = fmaf(c2[j], wr[j*3+2], a);
      }
      Ao[(h*11 + w)*224 + tid] = f2bf(a);
      S += a; Q += a*a;
      if (w < 10) {
#pragma unroll
        for (int j = 0; j < 9; ++j) {
          int kd = j / 3, kh = j - kd*3;
          c0[j] = c1[j]; c1[j] = c2[j];
          c2[j] = base[kd*169 + kh*13 + w + 3];
        }
      }
    }
  }
  ws[OFF_CP + b*448 + tid]       = S;
  ws[OFF_CP + b*448 + 224 + tid] = Q;
}

// ---------------- kd3: BN1 finalize ----------------
__global__ void kd3_bn1fin(const float* ws_in, float* ws,
                           const float* bn3g, const float* bn3b) {
  __shared__ float sS[256], sQ[256];
  int t = threadIdx.x;
  int o1 = t >> 5, j = t & 31;
  float S = 0.f, Q = 0.f;
  for (int b = j; b < 1024; b += 32) {
    const float* P = ws_in + OFF_CP + b*448 + o1*28;
    for (int dd = 0; dd < 28; ++dd) { S += P[dd]; Q += P[224 + dd]; }
  }
  sS[t] = S; sQ[t] = Q;
  __syncthreads();
  if (j == 0) {
    float Ss = 0.f, Qs = 0.f;
    for (int k = 0; k < 32; ++k) { Ss += sS[o1*32 + k]; Qs += sQ[o1*32 + k]; }
    float n = 3469312.f;
    float mean = Ss / n;
    float var = Qs / n - mean*mean;
    float sc = bn3g[o1] * rsqrtf(var + EPS);
    ws[OFF_ST + o1]     = sc;
    ws[OFF_ST + 8 + o1] = bn3b[o1] - mean*sc;
  }
}

// ---------------- k0wc: pack conv2 weights bf16 [oc][kpos][ci] ----------------
__global__ void k0wc(const float* c2w, float* ws) {
  int i = blockIdx.x*256 + threadIdx.x;
  if (i >= 129024) return;
  int ci = i % 224; int r = i / 224; int kpos = r % 9; int oc = r / 9;
  ((unsigned short*)(ws + OFF_WC))[i] = f2bf(c2w[oc*2016 + ci*9 + kpos]);
}

// ---------------- kd5 v4: conv2 MFMA, bf16 A in; fused BN2 partials out ----------------
__global__ __launch_bounds__(256) void kd5_conv2_mfma(const float* ws_in, const float* c2b,
                                                      float* ws) {
  __shared__ unsigned short InT[121*232];
  __shared__ float bn1s[224], bn1sh[224];
  const int tid  = threadIdx.x;
  const int b    = blockIdx.x;
  const int wid  = tid >> 6;
  const int lane = tid & 63;
  const int lane15 = lane & 15;
  const int kgrp   = lane >> 4;
  if (tid < 224) {
    int o1 = tid / 28;
    bn1s[tid]  = ws_in[OFF_ST + o1];
    bn1sh[tid] = ws_in[OFF_ST + 8 + o1];
  }
  __syncthreads();
  const unsigned short* Ab = (const unsigned short*)(ws_in + OFF_A) + (size_t)b*27104;
  for (int e = tid; e < 27104; e += 256) {
    int pos = e / 224, ci = e - pos*224;
    float v = fmaxf(bn1s[ci]*bf2f(Ab[e]) + bn1sh[ci], 0.f);
    InT[pos*232 + ci] = f2bf(v);
  }
  __syncthreads();

  int r0[6];
#pragma unroll
  for (int mt = 0; mt < 6; ++mt) {
    int s = mt*16 + lane15; if (s > 80) s = 80;
    int y = s / 9;
    r0[mt] = y*11 + (s - y*9);
  }
  const unsigned short* wcb = (const unsigned short*)(ws_in + OFF_WC);
  const int col = wid*16 + lane15;
  f32x4 acc[6];
#pragma unroll
  for (int mt = 0; mt < 6; ++mt) acc[mt] = (f32x4){0.f,0.f,0.f,0.f};

  for (int kpos = 0; kpos < 9; ++kpos) {
    int ki = kpos / 3, kj = kpos - ki*3;
    int roff = ki*11 + kj;
    const unsigned short* wcp = wcb + ((size_t)col*9 + kpos)*224 + kgrp*8;
#pragma unroll
    for (int Ks = 0; Ks < 7; ++Ks) {
      short8 bf = *(const short8*)(wcp + Ks*32);
#pragma unroll
      for (int mt = 0; mt < 6; ++mt) {
        short8 af = *(const short8*)(InT + (r0[mt] + roff)*232 + Ks*32 + kgrp*8);
        acc[mt] = __builtin_amdgcn_mfma_f32_16x16x32_bf16(af, bf, acc[mt], 0, 0, 0);
      }
    }
  }
  float bias = c2b[col];
  float* Bb = ws + OFF_B + (size_t)b*5184 + col*81;
  float S = 0.f, Q = 0.f;
#pragma unroll
  for (int mt = 0; mt < 6; ++mt) {
#pragma unroll
    for (int r = 0; r < 4; ++r) {
      int s = mt*16 + kgrp*4 + r;
      if (s < 81) {
        float v = acc[mt][r] + bias;
        Bb[s] = v;
        S += v; Q += v*v;
      }
    }
  }
  S += __shfl_xor(S, 16); S += __shfl_xor(S, 32);
  Q += __shfl_xor(Q, 16); Q += __shfl_xor(Q, 32);
  if (kgrp == 0) {
    ws[OFF_P + b*128 + col]      = S;
    ws[OFF_P + b*128 + 64 + col] = Q;
  }
}

// ---------------- kd7: BN2 finalize ----------------
__global__ void kd7_bn2fin(float* ws, const float* bn2g, const float* bn2b) {
  int t = threadIdx.x;
  float S = 0.f, Q = 0.f;
  for (int b = 0; b < 1024; ++b) {
    S += ws[OFF_P + b*128 + t];
    Q += ws[OFF_P + b*128 + 64 + t];
  }
  float n = 82944.f;
  float mean = S / n;
  float var = Q / n - mean * mean;
  float sc = bn2g[t] * rsqrtf(var + EPS);
  ws[OFF_ST + 16 + t] = sc;
  ws[OFF_ST + 80 + t] = bn2b[t] - mean * sc;
}

// ---------------- k0rot: rotary tables ----------------
__global__ void k0rot(float* ws) {
  int i = blockIdx.x * 256 + threadIdx.x;
  if (i >= 1296) return;
  int m = i / 648, r = i - m*648;
  int s = r >> 3, pp = r & 7;
  float scale = (2.f*pp + 6.4f) / 22.4f;
  float xs = powf(scale, (float)s / 512.f);
  float invf = powf(10000.f, -(float)pp / 8.f);
  float ang = (float)s * invf;
  float cx = cosf(ang), sn = sinf(ang);
  float cu = m ? cx/xs : cx*xs;
  float su = m ? sn/xs : sn*xs;
  ws[OFF_RT + i*2]     = cu;
  ws[OFF_RT + i*2 + 1] = su;
}

// ---------------- kd8: BN2 apply + relu + transpose -> X0 ----------------
__global__ __launch_bounds__(256) void kd8_tokens(float* ws) {
  int idx = blockIdx.x * 256 + threadIdx.x;
  if (idx >= 5308416) return;
  int o = idx % 64;
  int s = (idx / 64) % 81;
  int b = idx / 5184;
  float v = ws[OFF_ST + 16 + o] * ws[OFF_B + (size_t)b*5184 + o*81 + s] + ws[OFF_ST + 80 + o];
  ws[OFF_X0 + idx] = fmaxf(v, 0.f);
}

// ---------------- k0pack: bf16 col-major transformer weight pack into dead OFF_B ----------------
__global__ void k0pack(const float* wq, const float* wk, const float* wv,
                       const float* wg, const float* wo, const float* fw1,
                       const float* fw2, float* ws) {
  int i = blockIdx.x * 256 + threadIdx.x;
  unsigned short* wb = (unsigned short*)(ws + OFF_B);
  if (i < 24576) {                      // QKV: [(l*2+p)*96+col][k]
    int l = i / 12288, r = i % 12288;
    int p = r / 6144; r %= 6144;
    int col = r / 64, k = r % 64;
    int m = col >> 5, h2 = (col >> 4) & 1, kk = col & 15;
    const float* src = (m==0) ? wq : (m==1) ? wk : wv;
    wb[i] = f2bf(src[((l*4 + 2*p + h2)*64 + k)*16 + kk]);
  } else if (i < 32768) {               // WG
    int j = i - 24576;
    int l = j / 4096, col = (j / 64) & 63, k = j & 63;
    wb[i] = f2bf(wg[(l*64 + k)*64 + col]);
  } else if (i < 40960) {               // WO
    int j = i - 32768;
    int l = j / 4096, col = (j / 64) & 63, k = j & 63;
    wb[i] = f2bf(wo[(l*64 + k)*64 + col]);
  } else if (i < 57344) {               // FW1
    int j = i - 40960;
    int l = j / 8192, col = (j / 64) % 128, k = j & 63;
    wb[i] = f2bf(fw1[(l*64 + k)*128 + col]);
  } else if (i < 73728) {               // FW2
    int j = i - 57344;
    int l = j / 8192, col = (j / 128) & 63, k = j % 128;
    wb[i] = f2bf(fw2[(l*128 + k)*64 + col]);
  }
}

// ---------------- fa_layer v8: LDS diet (Hb stride 72; bf16 P buffers) -> 4 blocks/CU ----------------
// Layout (floats): Hb[96][72]u: 0..3456 | P0u[81][34]u: 3456 | P1u: 4833 | P2u: 6210 | P3u: 7587
//   | Zb[96][72]u at 6216 (16B-aligned; overlays dead P2/P3 + scratch to 9672) | muv 9672 | rsd 9753.
// XT fp32[81][64] overlays 3456..8640 (stage phase only). Total 9834 floats = 39.3 KB.
__global__ __launch_bounds__(256) void fa_layer(const float* ws_in, float* ws,
    const float* ln1g, const float* ln1b, const float* gng, const float* gnb, int l)
{
  __shared__ __align__(16) float sm[9834];
  unsigned short* Hb  = (unsigned short*)sm;           // [96][72]
  unsigned short* P0u = (unsigned short*)(sm + 3456);  // [81][34] bf16
  unsigned short* P1u = (unsigned short*)(sm + 4833);
  unsigned short* P2u = (unsigned short*)(sm + 6210);
  unsigned short* P3u = (unsigned short*)(sm + 7587);
  unsigned short* Zb  = (unsigned short*)(sm + 6216);  // [96][72] bf16
  float* XT  = sm + 3456;                              // [81][64] overlay
  float* muv = sm + 9672;
  float* rsd = sm + 9753;
  const int tid  = threadIdx.x;
  const int b    = blockIdx.x;
  const int wid  = tid >> 6;
  const int lane = tid & 63;
  const int lane15 = lane & 15;
  const int kgrp   = lane >> 4;
  const float* xg = ws_in + OFF_X0 + (size_t)b * 5184;
  const float* rtab = ws_in + OFF_RT;
  const unsigned short* wb = (const unsigned short*)(ws_in + OFF_B);

  for (int u = tid; u < 5184; u += 256) XT[u] = xg[u];
  __syncthreads();
  if (tid < 81) {
    const float* xr = XT + tid*64;
    float sv = 0.f;
    for (int d = 0; d < 64; ++d) sv += xr[d];
    float mean = sv * (1.f/64.f);
    float sq = 0.f;
    for (int d = 0; d < 64; ++d) { float dv = xr[d]-mean; sq += dv*dv; }
    muv[tid] = mean;
    rsd[tid] = rsqrtf(sq*(1.f/64.f) + EPS);
  }
  __syncthreads();
  for (int u = tid; u < 5184; u += 256) {
    int s = u >> 6, d = u & 63;
    Hb[s*72 + d] = f2bf((XT[u] - muv[s])*rsd[s]*ln1g[l*64+d] + ln1b[l*64+d]);
  }
  for (int e = tid; e < 1080; e += 256) Hb[81*72 + e] = 0;
  __syncthreads();   // XT dead

  for (int p = 0; p < 2; ++p) {
    unsigned short* QB = p ? P1u : P0u;
    unsigned short* KB = p ? P2u : P1u;
    unsigned short* VB = p ? P3u : P2u;
    const unsigned short* Bb = wb + WB_QKV + (size_t)(l*2 + p)*6144;
#pragma unroll
    for (int t = 0; t < 3; ++t) {
      int task = wid*3 + t;
      int Nt = task >> 1, mh = task & 1;
      f32x4 acc[3];
#pragma unroll
      for (int m3 = 0; m3 < 3; ++m3) acc[m3] = (f32x4){0.f,0.f,0.f,0.f};
#pragma unroll
      for (int Ks = 0; Ks < 2; ++Ks) {
        short8 bf = *(const short8*)(Bb + (size_t)(Nt*16 + lane15)*64 + Ks*32 + kgrp*8);
#pragma unroll
        for (int m3 = 0; m3 < 3; ++m3) {
          int r = (mh*3 + m3)*16 + lane15;
          short8 af = *(const short8*)(Hb + r*72 + Ks*32 + kgrp*8);
          acc[m3] = __builtin_amdgcn_mfma_f32_16x16x32_bf16(af, bf, acc[m3], 0, 0, 0);
        }
      }
      int col = Nt*16 + lane15;
      int m = col >> 5, idx = col & 31;
      unsigned short* dst = (m==0) ? QB : (m==1) ? KB : VB;
#pragma unroll
      for (int m3 = 0; m3 < 3; ++m3) {
#pragma unroll
        for (int r4 = 0; r4 < 4; ++r4) {
          int s = (mh*3 + m3)*16 + kgrp*4 + r4;
          if (s < 81) dst[s*34 + idx] = f2bf(acc[m3][r4]);
        }
      }
    }
    __syncthreads();
    for (int u = tid; u < 2592; u += 256) {
      int m = u / 1296;
      int rem = u - m*1296;
      int h2 = rem / 648;
      int r2 = rem - h2*648;
      int pp = r2 & 7, s = r2 >> 3;
      const float* rt = rtab + (m*648 + s*8 + pp)*2;
      float cu = rt[0], su = rt[1];
      unsigned short* ptr = (m ? KB : QB) + s*34 + h2*16 + 2*pp;
      float a = bf2f(ptr[0]), bb2 = bf2f(ptr[1]);
      ptr[0] = f2bf(a*cu - bb2*su);
      ptr[1] = f2bf(bb2*cu + a*su);
    }
    __syncthreads();
    if (tid < 162) {
      int h2 = tid & 1, s = tid >> 1;
      int hd = 2*p + h2;
      float g = 1.f - expf(-3.4657359f + (float)hd * (-0.92419624f));
      float lg = log2f(g);
      float q[16];
#pragma unroll
      for (int k = 0; k < 16; ++k) q[k] = bf2f(QB[s*34 + h2*16 + k]);
      float yh[16];
#pragma unroll
      for (int v = 0; v < 16; ++v) yh[v] = 0.f;
      for (int tt = 0; tt <= s; ++tt) {
        const unsigned short* Kr = KB + tt*34 + h2*16;
        float a = 0.f;
#pragma unroll
        for (int k = 0; k < 16; ++k) a = fmaf(q[k], bf2f(Kr[k]), a);
        a *= exp2f((float)(s - tt) * lg);
        const unsigned short* Vr = VB + tt*34 + h2*16;
#pragma unroll
        for (int v = 0; v < 16; ++v) yh[v] = fmaf(a, bf2f(Vr[v]), yh[v]);
      }
      float sv = 0.f;
#pragma unroll
      for (int v = 0; v < 16; ++v) sv += yh[v];
      float mean = sv * (1.f/16.f);
      float sq = 0.f;
#pragma unroll
      for (int v = 0; v < 16; ++v) { float dv = yh[v]-mean; sq += dv*dv; }
      float rstd = rsqrtf(sq*(1.f/16.f) + EPS);
#pragma unroll
      for (int v = 0; v < 16; ++v) {
        int col = hd*16 + v;
        QB[s*34 + h2*16 + v] = f2bf((yh[v]-mean)*rstd*gng[l*64+col] + gnb[l*64+col]);
      }
    }
    __syncthreads();
  }
  // P0u = gn heads 0,1; P1u = gn heads 2,3; P2u/P3u dead -> Zb

  {
    for (int e = tid; e < 1080; e += 256) Zb[81*72 + e] = 0;
    const unsigned short* Gb = wb + WB_WG + (size_t)l*4096;
    f32x4 acc[6];
#pragma unroll
    for (int mt = 0; mt < 6; ++mt) acc[mt] = (f32x4){0.f,0.f,0.f,0.f};
#pragma unroll
    for (int Ks = 0; Ks < 2; ++Ks) {
      short8 bf = *(const short8*)(Gb + (size_t)(wid*16 + lane15)*64 + Ks*32 + kgrp*8);
#pragma unroll
      for (int mt = 0; mt < 6; ++mt) {
        short8 af = *(const short8*)(Hb + (mt*16 + lane15)*72 + Ks*32 + kgrp*8);
        acc[mt] = __builtin_amdgcn_mfma_f32_16x16x32_bf16(af, bf, acc[mt], 0, 0, 0);
      }
    }
    int col = wid*16 + lane15;
    const unsigned short* gnb_ = (col < 32) ? P0u : P1u;
#pragma unroll
    for (int mt = 0; mt < 6; ++mt) {
#pragma unroll
      for (int r4 = 0; r4 < 4; ++r4) {
        int s = mt*16 + kgrp*4 + r4;
        if (s < 81) {
          float g = acc[mt][r4];
          float sig = 1.f/(1.f+expf(-g));
          Zb[s*72 + col] = f2bf(g*sig*bf2f(gnb_[s*34 + (col & 31)]));
        }
      }
    }
  }
  __syncthreads();

  {
    const unsigned short* Ob = wb + WB_WO + (size_t)l*4096;
    float* yg = ws + OFF_Y + (size_t)b * 5184;
    f32x4 acc[6];
#pragma unroll
    for (int mt = 0; mt < 6; ++mt) acc[mt] = (f32x4){0.f,0.f,0.f,0.f};
#pragma unroll
    for (int Ks = 0; Ks < 2; ++Ks) {
      short8 bf = *(const short8*)(Ob + (size_t)(wid*16 + lane15)*64 + Ks*32 + kgrp*8);
#pragma unroll
      for (int mt = 0; mt < 6; ++mt) {
        short8 af = *(const short8*)(Zb + (mt*16 + lane15)*72 + Ks*32 + kgrp*8);
        acc[mt] = __builtin_amdgcn_mfma_f32_16x16x32_bf16(af, bf, acc[mt], 0, 0, 0);
      }
    }
    int col = wid*16 + lane15;
#pragma unroll
    for (int mt = 0; mt < 6; ++mt) {
#pragma unroll
      for (int r4 = 0; r4 < 4; ++r4) {
        int s = mt*16 + kgrp*4 + r4;
        if (s < 81) {
          int u = s*64 + col;
          yg[u] = acc[mt][r4] + xg[u];
        }
      }
    }
  }
}

// ---------------- ff_layer v6: LDS diet (strides 72 / 136) -> 4 blocks/CU ----------------
// Layout (floats): H2b[96][72]u: 0..3456 | F1b[96][136]u: 3456..9984 | muv 9984 | rsd 10065.
// XT fp32[81][64] overlays 3456..8640 (stage only). Total 10146 floats = 40.6 KB.
__global__ __launch_bounds__(256) void ff_layer(const float* ws_in, float* ws,
    const float* fb1, const float* fb2, const float* ln2g, const float* ln2b, int l)
{
  __shared__ __align__(16) float sm[10146];
  unsigned short* H2b = (unsigned short*)sm;           // [96][72]
  unsigned short* F1b = (unsigned short*)(sm + 3456);  // [96][136]
  float* XT = sm + 3456;
  float* muv = sm + 9984;
  float* rsd = sm + 10065;
  const int tid  = threadIdx.x;
  const int b    = blockIdx.x;
  const int wid  = tid >> 6;
  const int lane = tid & 63;
  const int lane15 = lane & 15;
  const int kgrp   = lane >> 4;
  const float* yg = ws_in + OFF_Y + (size_t)b * 5184;
  const unsigned short* wb = (const unsigned short*)(ws_in + OFF_B);

  for (int u = tid; u < 5184; u += 256) XT[u] = yg[u];
  __syncthreads();
  if (tid < 81) {
    const float* xr = XT + tid*64;
    float sv = 0.f;
    for (int d = 0; d < 64; ++d) sv += xr[d];
    float mean = sv * (1.f/64.f);
    float sq = 0.f;
    for (int d = 0; d < 64; ++d) { float dv = xr[d]-mean; sq += dv*dv; }
    muv[tid] = mean;
    rsd[tid] = rsqrtf(sq*(1.f/64.f) + EPS);
  }
  __syncthreads();
  for (int u = tid; u < 5184; u += 256) {
    int s = u >> 6, d = u & 63;
    H2b[s*72 + d] = f2bf((XT[u] - muv[s])*rsd[s]*ln2g[l*64+d] + ln2b[l*64+d]);
  }
  for (int e = tid; e < 1080; e += 256) H2b[81*72 + e] = 0;
  __syncthreads();   // XT dead

  {
    for (int e = tid; e < 2040; e += 256) F1b[81*136 + e] = 0;
    const unsigned short* Wb1 = wb + WB_FW1 + (size_t)l*8192;
#pragma unroll
    for (int t = 0; t < 4; ++t) {
      int task = wid*4 + t;
      int Nt = task >> 1, mh = task & 1;
      f32x4 acc[3];
#pragma unroll
      for (int m3 = 0; m3 < 3; ++m3) acc[m3] = (f32x4){0.f,0.f,0.f,0.f};
#pragma unroll
      for (int Ks = 0; Ks < 2; ++Ks) {
        short8 bf = *(const short8*)(Wb1 + (size_t)(Nt*16 + lane15)*64 + Ks*32 + kgrp*8);
#pragma unroll
        for (int m3 = 0; m3 < 3; ++m3) {
          int r = (mh*3 + m3)*16 + lane15;
          short8 af = *(const short8*)(H2b + r*72 + Ks*32 + kgrp*8);
          acc[m3] = __builtin_amdgcn_mfma_f32_16x16x32_bf16(af, bf, acc[m3], 0, 0, 0);
        }
      }
      int col = Nt*16 + lane15;
#pragma unroll
      for (int m3 = 0; m3 < 3; ++m3) {
#pragma unroll
        for (int r4 = 0; r4 < 4; ++r4) {
          int s = (mh*3 + m3)*16 + kgrp*4 + r4;
          if (s < 81) {
            float pp = acc[m3][r4] + fb1[l*128 + col];
            F1b[s*136 + col] = f2bf(0.5f*pp*(1.f + erff(pp*0.70710678118f)));
          }
        }
      }
    }
  }
  __syncthreads();

  {
    const unsigned short* Wb2 = wb + WB_FW2 + (size_t)l*8192;
    float* xg = ws + OFF_X0 + (size_t)b * 5184;
    f32x4 acc[6];
#pragma unroll
    for (int mt = 0; mt < 6; ++mt) acc[mt] = (f32x4){0.f,0.f,0.f,0.f};
#pragma unroll
    for (int Ks = 0; Ks < 4; ++Ks) {
      short8 bf = *(const short8*)(Wb2 + (size_t)(wid*16 + lane15)*128 + Ks*32 + kgrp*8);
#pragma unroll
      for (int mt = 0; mt < 6; ++mt) {
        short8 af = *(const short8*)(F1b + (mt*16 + lane15)*136 + Ks*32 + kgrp*8);
        acc[mt] = __builtin_amdgcn_mfma_f32_16x16x32_bf16(af, bf, acc[mt], 0, 0, 0);
      }
    }
    int col = wid*16 + lane15;
#pragma unroll
    for (int mt = 0; mt < 6; ++mt) {
#pragma unroll
      for (int r4 = 0; r4 < 4; ++r4) {
        int s = mt*16 + kgrp*4 + r4;
        if (s < 81) {
          int u = s*64 + col;
          xg[u] = acc[mt][r4] + fb2[l*64 + col] + yg[u];
        }
      }
    }
  }
}

// ---------------- fcls: classifier ----------------
__global__ __launch_bounds__(256) void fcls(const float* ws_in, const float* nn1w,
                                            const float* nn1b, float* out) {
  __shared__ float red[256];
  const int tid = threadIdx.x;
  const int b = blockIdx.x;
  const float* Xr = ws_in + OFF_X0 + (size_t)b * 5184;
  int c = tid & 15, chunk = tid >> 4;
  int i0 = chunk * 324;
  float a = 0.f;
  for (int i = 0; i < 324; ++i)
    a = fmaf(Xr[i0+i], nn1w[(size_t)(i0+i)*16 + c], a);
  red[tid] = a;
  __syncthreads();
  if (tid < 16) {
    float s = nn1b[tid];
#pragma unroll
    for (int j = 0; j < 16; ++j) s += red[j*16 + tid];
    out[b*16 + tid] = s;
  }
}

// ---------------- launch ----------------
extern "C" void kernel_launch(void* const* d_in, const int* in_sizes, int n_in,
                              void* d_out, int out_size, void* d_ws, size_t ws_size,
                              hipStream_t stream) {
  const float* X    = (const float*)d_in[0];
  const float* c3w  = (const float*)d_in[1];
  const float* c3b  = (const float*)d_in[2];
  const float* bn3g = (const float*)d_in[3];
  const float* bn3b = (const float*)d_in[4];
  const float* c2w  = (const float*)d_in[5];
  const float* c2b  = (const float*)d_in[6];
  const float* bn2g = (const float*)d_in[7];
  const float* bn2b = (const float*)d_in[8];
  const float* wq   = (const float*)d_in[9];
  const float* wk   = (const float*)d_in[10];
  const float* wv   = (const float*)d_in[11];
  const float* wg   = (const float*)d_in[12];
  const float* wo   = (const float*)d_in[13];
  const float* gng  = (const float*)d_in[14];
  const float* gnb  = (const float*)d_in[15];
  const float* ln1g = (const float*)d_in[16];
  const float* ln1b = (const float*)d_in[17];
  const float* ln2g = (const float*)d_in[18];
  const float* ln2b = (const float*)d_in[19];
  const float* fw1  = (const float*)d_in[20];
  const float* fb1  = (const float*)d_in[21];
  const float* fw2  = (const float*)d_in[22];
  const float* fb2  = (const float*)d_in[23];
  const float* nn1w = (const float*)d_in[24];
  const float* nn1b = (const float*)d_in[25];
  float* ws = (float*)d_ws;
  float* out = (float*)d_out;

  // conv stage
  k0wc<<<504, 256, 0, stream>>>(c2w, ws);
  kd1_conv1<<<1024, 256, 0, stream>>>(X, c3w, c3b, ws);
  kd3_bn1fin<<<1, 256, 0, stream>>>(ws, ws, bn3g, bn3b);
  kd5_conv2_mfma<<<1024, 256, 0, stream>>>(ws, c2b, ws);
  kd7_bn2fin<<<1, 64, 0, stream>>>(ws, bn2g, bn2b);
  k0rot<<<6, 256, 0, stream>>>(ws);
  kd8_tokens<<<20736, 256, 0, stream>>>(ws);
  k0pack<<<288, 256, 0, stream>>>(wq, wk, wv, wg, wo, fw1, fw2, ws);

  // transformer layers
  for (int l = 0; l < 2; ++l) {
    fa_layer<<<1024, 256, 0, stream>>>(ws, ws, ln1g, ln1b, gng, gnb, l);
    ff_layer<<<1024, 256, 0, stream>>>(ws, ws, fb1, fb2, ln2g, ln2b, l);
  }

  fcls<<<1024, 256, 0, stream>>>(ws, nn1w, nn1b, out);
}

// Round 20
// 531.910 us; speedup vs baseline: 1.1560x; 1.1560x over previous
//
#include <hip/hip_runtime.h>
#include <math.h>

#define EPS 1e-5f

// ---------------- float offsets in ws ----------------
#define OFF_A  0u          // conv1 out bf16 CHANNEL-LAST ushort[1024][121][224] (dead after kd5)
#define OFF_X0 0u          // tokens x [1024][81][64] fp32 (written after A dead)
#define OFF_Y  31850496u   // y [1024][81][64]
#define OFF_CP 31850496u   // BN1 partials [1024][448] (dead before fa writes Y)
#define OFF_WC 32374784u   // packed conv2 bf16 weights [64][9][224] ushort
#define OFF_B  47775744u   // conv2 out; after kd8: packed bf16 transformer weights
#define OFF_P  53084160u   // BN2 partials (dead after kd7 -> rotary table)
#define OFF_RT 53084160u   // rotary table [m 2][s 81][p 8][cu,su]
#define OFF_ST 53215232u   // scale1[8] shift1[8] scale2[64] shift2[64]

// packed bf16 transformer weight offsets (ushort units, base = (ushort*)(ws+OFF_B))
#define WB_QKV 0u          // [(l*2+p)*96+col]*64+k
#define WB_WG  24576u
#define WB_WO  32768u
#define WB_FW1 40960u
#define WB_FW2 57344u

typedef __attribute__((ext_vector_type(8))) short short8;
typedef __attribute__((ext_vector_type(4))) float f32x4;

__device__ inline unsigned short f2bf(float f) {
  unsigned int x = __float_as_uint(f);
  unsigned int r = x + 0x7fffu + ((x >> 16) & 1u);
  return (unsigned short)(r >> 16);
}
__device__ inline float bf2f(unsigned short h) {
  return __uint_as_float(((unsigned int)h) << 16);
}

// ---------------- kd1 v3: conv3d + bias -> A bf16 channel-last; fused BN1 partials ----------------
// thread = ci (224 active); 27 weights in regs; rolling 3-col window; coalesced stores.
__global__ __launch_bounds__(256) void kd1_conv1(const float* X, const float* c3w,
                                                 const float* c3b, float* ws) {
  __shared__ float Xi[5070];
  __shared__ float w3[216];
  int tid = threadIdx.x, b = blockIdx.x;
  for (int u = tid; u < 5070; u += 256) Xi[u] = X[(size_t)b*5070 + u];
  if (tid < 216) w3[tid] = c3w[tid];
  __syncthreads();
  if (tid >= 224) return;
  int o1 = tid / 28, dd = tid - o1*28;
  float wr[27];
#pragma unroll
  for (int k = 0; k < 27; ++k) wr[k] = w3[o1*27 + k];
  float bias = c3b[o1];
  unsigned short* Ao = (unsigned short*)(ws + OFF_A) + (size_t)b*27104;
  float S = 0.f, Q = 0.f;
  for (int h = 0; h < 11; ++h) {
    const float* base = Xi + dd*169 + h*13;
    float c0[9], c1[9], c2[9];
#pragma unroll
    for (int j = 0; j < 9; ++j) {
      int kd = j / 3, kh = j - kd*3;
      const float* rp = base + kd*169 + kh*13;
      c0[j] = rp[0]; c1[j] = rp[1]; c2[j] = rp[2];
    }
#pragma unroll
    for (int w = 0; w < 11; ++w) {
      float a = bias;
#pragma unroll
      for (int j = 0; j < 9; ++j) {
        a = fmaf(c0[j], wr[j*3+0], a);
        a = fmaf(c1[j], wr[j*3+1], a);
        a = fmaf(c2[j], wr[j*3+2], a);
      }
      Ao[(h*11 + w)*224 + tid] = f2bf(a);
      S += a; Q += a*a;
      if (w < 10) {
#pragma unroll
        for (int j = 0; j < 9; ++j) {
          int kd = j / 3, kh = j - kd*3;
          c0[j] = c1[j]; c1[j] = c2[j];
          c2[j] = base[kd*169 + kh*13 + w + 3];
        }
      }
    }
  }
  ws[OFF_CP + b*448 + tid]       = S;
  ws[OFF_CP + b*448 + 224 + tid] = Q;
}

// ---------------- kd3: BN1 finalize (1 block, 256 threads) ----------------
__global__ void kd3_bn1fin(const float* ws_in, float* ws,
                           const float* bn3g, const float* bn3b) {
  __shared__ float sS[256], sQ[256];
  int t = threadIdx.x;
  int o1 = t >> 5, j = t & 31;
  float S = 0.f, Q = 0.f;
  for (int b = j; b < 1024; b += 32) {
    const float* P = ws_in + OFF_CP + b*448 + o1*28;
    for (int dd = 0; dd < 28; ++dd) { S += P[dd]; Q += P[224 + dd]; }
  }
  sS[t] = S; sQ[t] = Q;
  __syncthreads();
  if (j == 0) {
    float Ss = 0.f, Qs = 0.f;
    for (int k = 0; k < 32; ++k) { Ss += sS[o1*32 + k]; Qs += sQ[o1*32 + k]; }
    float n = 3469312.f;
    float mean = Ss / n;
    float var = Qs / n - mean*mean;
    float sc = bn3g[o1] * rsqrtf(var + EPS);
    ws[OFF_ST + o1]     = sc;
    ws[OFF_ST + 8 + o1] = bn3b[o1] - mean*sc;
  }
}

// ---------------- k0wc: pack conv2 weights bf16 [oc][kpos][ci] ----------------
__global__ void k0wc(const float* c2w, float* ws) {
  int i = blockIdx.x*256 + threadIdx.x;
  if (i >= 129024) return;
  int ci = i % 224; int r = i / 224; int kpos = r % 9; int oc = r / 9;
  ((unsigned short*)(ws + OFF_WC))[i] = f2bf(c2w[oc*2016 + ci*9 + kpos]);
}

// ---------------- kd5 v4: conv2 MFMA, bf16 A in; fused BN2 partials out ----------------
__global__ __launch_bounds__(256) void kd5_conv2_mfma(const float* ws_in, const float* c2b,
                                                      float* ws) {
  __shared__ unsigned short InT[121*232];   // 56.1 KB
  __shared__ float bn1s[224], bn1sh[224];
  const int tid  = threadIdx.x;
  const int b    = blockIdx.x;
  const int wid  = tid >> 6;
  const int lane = tid & 63;
  const int lane15 = lane & 15;
  const int kgrp   = lane >> 4;
  if (tid < 224) {
    int o1 = tid / 28;
    bn1s[tid]  = ws_in[OFF_ST + o1];
    bn1sh[tid] = ws_in[OFF_ST + 8 + o1];
  }
  __syncthreads();
  const unsigned short* Ab = (const unsigned short*)(ws_in + OFF_A) + (size_t)b*27104;
  for (int e = tid; e < 27104; e += 256) {
    int pos = e / 224, ci = e - pos*224;
    float v = fmaxf(bn1s[ci]*bf2f(Ab[e]) + bn1sh[ci], 0.f);
    InT[pos*232 + ci] = f2bf(v);
  }
  __syncthreads();

  int r0[6];
#pragma unroll
  for (int mt = 0; mt < 6; ++mt) {
    int s = mt*16 + lane15; if (s > 80) s = 80;
    int y = s / 9;
    r0[mt] = y*11 + (s - y*9);
  }
  const unsigned short* wcb = (const unsigned short*)(ws_in + OFF_WC);
  const int col = wid*16 + lane15;
  f32x4 acc[6];
#pragma unroll
  for (int mt = 0; mt < 6; ++mt) acc[mt] = (f32x4){0.f,0.f,0.f,0.f};

  for (int kpos = 0; kpos < 9; ++kpos) {
    int ki = kpos / 3, kj = kpos - ki*3;
    int roff = ki*11 + kj;
    const unsigned short* wcp = wcb + ((size_t)col*9 + kpos)*224 + kgrp*8;
#pragma unroll
    for (int Ks = 0; Ks < 7; ++Ks) {
      short8 bf = *(const short8*)(wcp + Ks*32);
#pragma unroll
      for (int mt = 0; mt < 6; ++mt) {
        short8 af = *(const short8*)(InT + (r0[mt] + roff)*232 + Ks*32 + kgrp*8);
        acc[mt] = __builtin_amdgcn_mfma_f32_16x16x32_bf16(af, bf, acc[mt], 0, 0, 0);
      }
    }
  }
  // epilogue: bias + store B + fused BN2 partials (reduce over kgrp)
  float bias = c2b[col];
  float* Bb = ws + OFF_B + (size_t)b*5184 + col*81;
  float S = 0.f, Q = 0.f;
#pragma unroll
  for (int mt = 0; mt < 6; ++mt) {
#pragma unroll
    for (int r = 0; r < 4; ++r) {
      int s = mt*16 + kgrp*4 + r;
      if (s < 81) {
        float v = acc[mt][r] + bias;
        Bb[s] = v;
        S += v; Q += v*v;
      }
    }
  }
  S += __shfl_xor(S, 16); S += __shfl_xor(S, 32);
  Q += __shfl_xor(Q, 16); Q += __shfl_xor(Q, 32);
  if (kgrp == 0) {
    ws[OFF_P + b*128 + col]      = S;
    ws[OFF_P + b*128 + 64 + col] = Q;
  }
}

// ---------------- kd7: BN2 finalize ----------------
__global__ void kd7_bn2fin(float* ws, const float* bn2g, const float* bn2b) {
  int t = threadIdx.x;
  float S = 0.f, Q = 0.f;
  for (int b = 0; b < 1024; ++b) {
    S += ws[OFF_P + b*128 + t];
    Q += ws[OFF_P + b*128 + 64 + t];
  }
  float n = 82944.f;
  float mean = S / n;
  float var = Q / n - mean * mean;
  float sc = bn2g[t] * rsqrtf(var + EPS);
  ws[OFF_ST + 16 + t] = sc;
  ws[OFF_ST + 80 + t] = bn2b[t] - mean * sc;
}

// ---------------- k0rot: rotary tables ----------------
__global__ void k0rot(float* ws) {
  int i = blockIdx.x * 256 + threadIdx.x;
  if (i >= 1296) return;
  int m = i / 648, r = i - m*648;
  int s = r >> 3, pp = r & 7;
  float scale = (2.f*pp + 6.4f) / 22.4f;
  float xs = powf(scale, (float)s / 512.f);
  float invf = powf(10000.f, -(float)pp / 8.f);
  float ang = (float)s * invf;
  float cx = cosf(ang), sn = sinf(ang);
  float cu = m ? cx/xs : cx*xs;
  float su = m ? sn/xs : sn*xs;
  ws[OFF_RT + i*2]     = cu;
  ws[OFF_RT + i*2 + 1] = su;
}

// ---------------- kd8: BN2 apply + relu + transpose -> X0 ----------------
__global__ __launch_bounds__(256) void kd8_tokens(float* ws) {
  int idx = blockIdx.x * 256 + threadIdx.x;
  if (idx >= 5308416) return;
  int o = idx % 64;
  int s = (idx / 64) % 81;
  int b = idx / 5184;
  float v = ws[OFF_ST + 16 + o] * ws[OFF_B + (size_t)b*5184 + o*81 + s] + ws[OFF_ST + 80 + o];
  ws[OFF_X0 + idx] = fmaxf(v, 0.f);
}

// ---------------- k0pack: bf16 col-major transformer weight pack into dead OFF_B ----------------
__global__ void k0pack(const float* wq, const float* wk, const float* wv,
                       const float* wg, const float* wo, const float* fw1,
                       const float* fw2, float* ws) {
  int i = blockIdx.x * 256 + threadIdx.x;
  unsigned short* wb = (unsigned short*)(ws + OFF_B);
  if (i < 24576) {                      // QKV: [(l*2+p)*96+col][k]
    int l = i / 12288, r = i % 12288;
    int p = r / 6144; r %= 6144;
    int col = r / 64, k = r % 64;
    int m = col >> 5, h2 = (col >> 4) & 1, kk = col & 15;
    const float* src = (m==0) ? wq : (m==1) ? wk : wv;
    wb[i] = f2bf(src[((l*4 + 2*p + h2)*64 + k)*16 + kk]);
  } else if (i < 32768) {               // WG
    int j = i - 24576;
    int l = j / 4096, col = (j / 64) & 63, k = j & 63;
    wb[i] = f2bf(wg[(l*64 + k)*64 + col]);
  } else if (i < 40960) {               // WO
    int j = i - 32768;
    int l = j / 4096, col = (j / 64) & 63, k = j & 63;
    wb[i] = f2bf(wo[(l*64 + k)*64 + col]);
  } else if (i < 57344) {               // FW1
    int j = i - 40960;
    int l = j / 8192, col = (j / 64) % 128, k = j & 63;
    wb[i] = f2bf(fw1[(l*64 + k)*128 + col]);
  } else if (i < 73728) {               // FW2
    int j = i - 57344;
    int l = j / 8192, col = (j / 128) & 63, k = j % 128;
    wb[i] = f2bf(fw2[(l*128 + k)*64 + col]);
  }
}

// ---------------- fa_layer v6 (R14/R18 known-good): MFMA proj/gate/wo; scalar retention ----------------
__global__ __launch_bounds__(256) void fa_layer(const float* ws_in, float* ws,
    const float* ln1g, const float* ln1b, const float* gng, const float* gnb, int l)
{
  __shared__ __align__(16) float sm[15018];
  unsigned short* Hb = (unsigned short*)sm;       // [96][80]
  float* P0 = sm + 3840;
  float* P1 = sm + 6594;
  float* P2 = sm + 9348;
  float* P3 = sm + 12102;
  float* XT = sm + 3840;                          // [81][64] overlay P0/P1
  unsigned short* Zb = (unsigned short*)(sm + 9348);  // [96][80] overlay P2/P3
  float* muv = sm + 14856;
  float* rsd = sm + 14937;
  const int tid  = threadIdx.x;
  const int b    = blockIdx.x;
  const int wid  = tid >> 6;
  const int lane = tid & 63;
  const int lane15 = lane & 15;
  const int kgrp   = lane >> 4;
  const float* xg = ws_in + OFF_X0 + (size_t)b * 5184;
  const float* rtab = ws_in + OFF_RT;
  const unsigned short* wb = (const unsigned short*)(ws_in + OFF_B);

  for (int u = tid; u < 5184; u += 256) XT[u] = xg[u];
  __syncthreads();
  if (tid < 81) {
    const float* xr = XT + tid*64;
    float sv = 0.f;
    for (int d = 0; d < 64; ++d) sv += xr[d];
    float mean = sv * (1.f/64.f);
    float sq = 0.f;
    for (int d = 0; d < 64; ++d) { float dv = xr[d]-mean; sq += dv*dv; }
    muv[tid] = mean;
    rsd[tid] = rsqrtf(sq*(1.f/64.f) + EPS);
  }
  __syncthreads();
  for (int u = tid; u < 5184; u += 256) {
    int s = u >> 6, d = u & 63;
    Hb[s*80 + d] = f2bf((XT[u] - muv[s])*rsd[s]*ln1g[l*64+d] + ln1b[l*64+d]);
  }
  for (int e = tid; e < 1200; e += 256) Hb[81*80 + e] = 0;
  __syncthreads();

  for (int p = 0; p < 2; ++p) {
    float* QB = p ? P1 : P0;
    float* KB = p ? P2 : P1;
    float* VB = p ? P3 : P2;
    const unsigned short* Bb = wb + WB_QKV + (size_t)(l*2 + p)*6144;
#pragma unroll
    for (int t = 0; t < 3; ++t) {
      int task = wid*3 + t;
      int Nt = task >> 1, mh = task & 1;
      f32x4 acc[3];
#pragma unroll
      for (int m3 = 0; m3 < 3; ++m3) acc[m3] = (f32x4){0.f,0.f,0.f,0.f};
#pragma unroll
      for (int Ks = 0; Ks < 2; ++Ks) {
        short8 bf = *(const short8*)(Bb + (size_t)(Nt*16 + lane15)*64 + Ks*32 + kgrp*8);
#pragma unroll
        for (int m3 = 0; m3 < 3; ++m3) {
          int r = (mh*3 + m3)*16 + lane15;
          short8 af = *(const short8*)(Hb + r*80 + Ks*32 + kgrp*8);
          acc[m3] = __builtin_amdgcn_mfma_f32_16x16x32_bf16(af, bf, acc[m3], 0, 0, 0);
        }
      }
      int col = Nt*16 + lane15;
      int m = col >> 5, idx = col & 31;
      float* dst = (m==0) ? QB : (m==1) ? KB : VB;
#pragma unroll
      for (int m3 = 0; m3 < 3; ++m3) {
#pragma unroll
        for (int r4 = 0; r4 < 4; ++r4) {
          int s = (mh*3 + m3)*16 + kgrp*4 + r4;
          if (s < 81) dst[s*34 + idx] = acc[m3][r4];
        }
      }
    }
    __syncthreads();
    for (int u = tid; u < 2592; u += 256) {
      int m = u / 1296;
      int rem = u - m*1296;
      int h2 = rem / 648;
      int r2 = rem - h2*648;
      int pp = r2 & 7, s = r2 >> 3;
      const float* rt = rtab + (m*648 + s*8 + pp)*2;
      float cu = rt[0], su = rt[1];
      float* ptr = (m ? KB : QB) + s*34 + h2*16 + 2*pp;
      float a = ptr[0], bb2 = ptr[1];
      ptr[0] = a*cu - bb2*su;
      ptr[1] = bb2*cu + a*su;
    }
    __syncthreads();
    if (tid < 162) {
      int h2 = tid & 1, s = tid >> 1;
      int hd = 2*p + h2;
      float g = 1.f - expf(-3.4657359f + (float)hd * (-0.92419624f));
      float lg = log2f(g);
      float q[16];
#pragma unroll
      for (int k = 0; k < 16; ++k) q[k] = QB[s*34 + h2*16 + k];
      float yh[16];
#pragma unroll
      for (int v = 0; v < 16; ++v) yh[v] = 0.f;
      for (int tt = 0; tt <= s; ++tt) {
        const float* Kr = KB + tt*34 + h2*16;
        float a = 0.f;
#pragma unroll
        for (int k = 0; k < 16; ++k) a = fmaf(q[k], Kr[k], a);
        a *= exp2f((float)(s - tt) * lg);
        const float* Vr = VB + tt*34 + h2*16;
#pragma unroll
        for (int v = 0; v < 16; ++v) yh[v] = fmaf(a, Vr[v], yh[v]);
      }
      float sv = 0.f;
#pragma unroll
      for (int v = 0; v < 16; ++v) sv += yh[v];
      float mean = sv * (1.f/16.f);
      float sq = 0.f;
#pragma unroll
      for (int v = 0; v < 16; ++v) { float dv = yh[v]-mean; sq += dv*dv; }
      float rstd = rsqrtf(sq*(1.f/16.f) + EPS);
#pragma unroll
      for (int v = 0; v < 16; ++v) {
        int col = hd*16 + v;
        QB[s*34 + h2*16 + v] = (yh[v]-mean)*rstd*gng[l*64+col] + gnb[l*64+col];
      }
    }
    __syncthreads();
  }

  {
    for (int e = tid; e < 1200; e += 256) Zb[81*80 + e] = 0;
    const unsigned short* Gb = wb + WB_WG + (size_t)l*4096;
    f32x4 acc[6];
#pragma unroll
    for (int mt = 0; mt < 6; ++mt) acc[mt] = (f32x4){0.f,0.f,0.f,0.f};
#pragma unroll
    for (int Ks = 0; Ks < 2; ++Ks) {
      short8 bf = *(const short8*)(Gb + (size_t)(wid*16 + lane15)*64 + Ks*32 + kgrp*8);
#pragma unroll
      for (int mt = 0; mt < 6; ++mt) {
        short8 af = *(const short8*)(Hb + (mt*16 + lane15)*80 + Ks*32 + kgrp*8);
        acc[mt] = __builtin_amdgcn_mfma_f32_16x16x32_bf16(af, bf, acc[mt], 0, 0, 0);
      }
    }
    int col = wid*16 + lane15;
    const float* gnb_ = (col < 32) ? P0 : P1;
#pragma unroll
    for (int mt = 0; mt < 6; ++mt) {
#pragma unroll
      for (int r4 = 0; r4 < 4; ++r4) {
        int s = mt*16 + kgrp*4 + r4;
        if (s < 81) {
          float g = acc[mt][r4];
          float sig = 1.f/(1.f+expf(-g));
          Zb[s*80 + col] = f2bf(g*sig*gnb_[s*34 + (col & 31)]);
        }
      }
    }
  }
  __syncthreads();

  {
    const unsigned short* Ob = wb + WB_WO + (size_t)l*4096;
    float* yg = ws + OFF_Y + (size_t)b * 5184;
    f32x4 acc[6];
#pragma unroll
    for (int mt = 0; mt < 6; ++mt) acc[mt] = (f32x4){0.f,0.f,0.f,0.f};
#pragma unroll
    for (int Ks = 0; Ks < 2; ++Ks) {
      short8 bf = *(const short8*)(Ob + (size_t)(wid*16 + lane15)*64 + Ks*32 + kgrp*8);
#pragma unroll
      for (int mt = 0; mt < 6; ++mt) {
        short8 af = *(const short8*)(Zb + (mt*16 + lane15)*80 + Ks*32 + kgrp*8);
        acc[mt] = __builtin_amdgcn_mfma_f32_16x16x32_bf16(af, bf, acc[mt], 0, 0, 0);
      }
    }
    int col = wid*16 + lane15;
#pragma unroll
    for (int mt = 0; mt < 6; ++mt) {
#pragma unroll
      for (int r4 = 0; r4 < 4; ++r4) {
        int s = mt*16 + kgrp*4 + r4;
        if (s < 81) {
          int u = s*64 + col;
          yg[u] = acc[mt][r4] + xg[u];
        }
      }
    }
  }
}

// ---------------- ff_layer v5: MFMA fw1/fw2 ----------------
__global__ __launch_bounds__(256) void ff_layer(const float* ws_in, float* ws,
    const float* fb1, const float* fb2, const float* ln2g, const float* ln2b, int l)
{
  __shared__ __align__(16) float sm[10914];
  unsigned short* H2b = (unsigned short*)sm;       // [96][80]
  unsigned short* F1b = (unsigned short*)(sm + 3840);  // [96][144]
  float* XT = sm + 3840;
  float* muv = sm + 10752;
  float* rsd = sm + 10833;
  const int tid  = threadIdx.x;
  const int b    = blockIdx.x;
  const int wid  = tid >> 6;
  const int lane = tid & 63;
  const int lane15 = lane & 15;
  const int kgrp   = lane >> 4;
  const float* yg = ws_in + OFF_Y + (size_t)b * 5184;
  const unsigned short* wb = (const unsigned short*)(ws_in + OFF_B);

  for (int u = tid; u < 5184; u += 256) XT[u] = yg[u];
  __syncthreads();
  if (tid < 81) {
    const float* xr = XT + tid*64;
    float sv = 0.f;
    for (int d = 0; d < 64; ++d) sv += xr[d];
    float mean = sv * (1.f/64.f);
    float sq = 0.f;
    for (int d = 0; d < 64; ++d) { float dv = xr[d]-mean; sq += dv*dv; }
    muv[tid] = mean;
    rsd[tid] = rsqrtf(sq*(1.f/64.f) + EPS);
  }
  __syncthreads();
  for (int u = tid; u < 5184; u += 256) {
    int s = u >> 6, d = u & 63;
    H2b[s*80 + d] = f2bf((XT[u] - muv[s])*rsd[s]*ln2g[l*64+d] + ln2b[l*64+d]);
  }
  for (int e = tid; e < 1200; e += 256) H2b[81*80 + e] = 0;
  __syncthreads();

  {
    for (int e = tid; e < 2160; e += 256) F1b[81*144 + e] = 0;
    const unsigned short* Wb1 = wb + WB_FW1 + (size_t)l*8192;
#pragma unroll
    for (int t = 0; t < 4; ++t) {
      int task = wid*4 + t;
      int Nt = task >> 1, mh = task & 1;
      f32x4 acc[3];
#pragma unroll
      for (int m3 = 0; m3 < 3; ++m3) acc[m3] = (f32x4){0.f,0.f,0.f,0.f};
#pragma unroll
      for (int Ks = 0; Ks < 2; ++Ks) {
        short8 bf = *(const short8*)(Wb1 + (size_t)(Nt*16 + lane15)*64 + Ks*32 + kgrp*8);
#pragma unroll
        for (int m3 = 0; m3 < 3; ++m3) {
          int r = (mh*3 + m3)*16 + lane15;
          short8 af = *(const short8*)(H2b + r*80 + Ks*32 + kgrp*8);
          acc[m3] = __builtin_amdgcn_mfma_f32_16x16x32_bf16(af, bf, acc[m3], 0, 0, 0);
        }
      }
      int col = Nt*16 + lane15;
#pragma unroll
      for (int m3 = 0; m3 < 3; ++m3) {
#pragma unroll
        for (int r4 = 0; r4 < 4; ++r4) {
          int s = (mh*3 + m3)*16 + kgrp*4 + r4;
          if (s < 81) {
            float pp = acc[m3][r4] + fb1[l*128 + col];
            F1b[s*144 + col] = f2bf(0.5f*pp*(1.f + erff(pp*0.70710678118f)));
          }
        }
      }
    }
  }
  __syncthreads();

  {
    const unsigned short* Wb2 = wb + WB_FW2 + (size_t)l*8192;
    float* xg = ws + OFF_X0 + (size_t)b * 5184;
    f32x4 acc[6];
#pragma unroll
    for (int mt = 0; mt < 6; ++mt) acc[mt] = (f32x4){0.f,0.f,0.f,0.f};
#pragma unroll
    for (int Ks = 0; Ks < 4; ++Ks) {
      short8 bf = *(const short8*)(Wb2 + (size_t)(wid*16 + lane15)*128 + Ks*32 + kgrp*8);
#pragma unroll
      for (int mt = 0; mt < 6; ++mt) {
        short8 af = *(const short8*)(F1b + (mt*16 + lane15)*144 + Ks*32 + kgrp*8);
        acc[mt] = __builtin_amdgcn_mfma_f32_16x16x32_bf16(af, bf, acc[mt], 0, 0, 0);
      }
    }
    int col = wid*16 + lane15;
#pragma unroll
    for (int mt = 0; mt < 6; ++mt) {
#pragma unroll
      for (int r4 = 0; r4 < 4; ++r4) {
        int s = mt*16 + kgrp*4 + r4;
        if (s < 81) {
          int u = s*64 + col;
          xg[u] = acc[mt][r4] + fb2[l*64 + col] + yg[u];
        }
      }
    }
  }
}

// ---------------- fcls: classifier ----------------
__global__ __launch_bounds__(256) void fcls(const float* ws_in, const float* nn1w,
                                            const float* nn1b, float* out) {
  __shared__ float red[256];
  const int tid = threadIdx.x;
  const int b = blockIdx.x;
  const float* Xr = ws_in + OFF_X0 + (size_t)b * 5184;
  int c = tid & 15, chunk = tid >> 4;
  int i0 = chunk * 324;
  float a = 0.f;
  for (int i = 0; i < 324; ++i)
    a = fmaf(Xr[i0+i], nn1w[(size_t)(i0+i)*16 + c], a);
  red[tid] = a;
  __syncthreads();
  if (tid < 16) {
    float s = nn1b[tid];
#pragma unroll
    for (int j = 0; j < 16; ++j) s += red[j*16 + tid];
    out[b*16 + tid] = s;
  }
}

// ---------------- launch ----------------
extern "C" void kernel_launch(void* const* d_in, const int* in_sizes, int n_in,
                              void* d_out, int out_size, void* d_ws, size_t ws_size,
                              hipStream_t stream) {
  const float* X    = (const float*)d_in[0];
  const float* c3w  = (const float*)d_in[1];
  const float* c3b  = (const float*)d_in[2];
  const float* bn3g = (const float*)d_in[3];
  const float* bn3b = (const float*)d_in[4];
  const float* c2w  = (const float*)d_in[5];
  const float* c2b  = (const float*)d_in[6];
  const float* bn2g = (const float*)d_in[7];
  const float* bn2b = (const float*)d_in[8];
  const float* wq   = (const float*)d_in[9];
  const float* wk   = (const float*)d_in[10];
  const float* wv   = (const float*)d_in[11];
  const float* wg   = (const float*)d_in[12];
  const float* wo   = (const float*)d_in[13];
  const float* gng  = (const float*)d_in[14];
  const float* gnb  = (const float*)d_in[15];
  const float* ln1g = (const float*)d_in[16];
  const float* ln1b = (const float*)d_in[17];
  const float* ln2g = (const float*)d_in[18];
  const float* ln2b = (const float*)d_in[19];
  const float* fw1  = (const float*)d_in[20];
  const float* fb1  = (const float*)d_in[21];
  const float* fw2  = (const float*)d_in[22];
  const float* fb2  = (const float*)d_in[23];
  const float* nn1w = (const float*)d_in[24];
  const float* nn1b = (const float*)d_in[25];
  float* ws = (float*)d_ws;
  float* out = (float*)d_out;

  // conv stage
  k0wc<<<504, 256, 0, stream>>>(c2w, ws);
  kd1_conv1<<<1024, 256, 0, stream>>>(X, c3w, c3b, ws);      // fused BN1 partials, bf16 A
  kd3_bn1fin<<<1, 256, 0, stream>>>(ws, ws, bn3g, bn3b);
  kd5_conv2_mfma<<<1024, 256, 0, stream>>>(ws, c2b, ws);     // fused BN2 partials
  kd7_bn2fin<<<1, 64, 0, stream>>>(ws, bn2g, bn2b);
  k0rot<<<6, 256, 0, stream>>>(ws);
  kd8_tokens<<<20736, 256, 0, stream>>>(ws);
  k0pack<<<288, 256, 0, stream>>>(wq, wk, wv, wg, wo, fw1, fw2, ws);

  // transformer layers (fused per-batch, MFMA proj/gate/wo + scalar retention)
  for (int l = 0; l < 2; ++l) {
    fa_layer<<<1024, 256, 0, stream>>>(ws, ws, ln1g, ln1b, gng, gnb, l);
    ff_layer<<<1024, 256, 0, stream>>>(ws, ws, fb1, fb2, ln2g, ln2b, l);
  }

  fcls<<<1024, 256, 0, stream>>>(ws, nn1w, nn1b, out);
}